// Round 1
// baseline (660.880 us; speedup 1.0000x reference)
//
#include <hip/hip_runtime.h>

#define DFEAT 64
#define NG 64

// ---------------- init: deg=1 (self loop), zero sums/cnt ----------------
__global__ void k_init(float* __restrict__ deg, float* __restrict__ sums,
                       float* __restrict__ cntf, int n) {
  int i = blockIdx.x * 256 + threadIdx.x;
  if (i < n) deg[i] = 1.0f;
  if (i < NG * DFEAT) sums[i] = 0.0f;
  if (i < NG) cntf[i] = 0.0f;
}

// ---------------- in-degree accumulation over edge targets ----------------
__global__ void k_deg(const int* __restrict__ col, float* __restrict__ deg, int e) {
  int i = blockIdx.x * 256 + threadIdx.x;
  if (i < e) unsafeAtomicAdd(&deg[col[i]], 1.0f);
}

// ---------------- deg -> rsqrt(deg) in place ----------------
__global__ void k_rsqrt(float* __restrict__ deg, int n) {
  int i = blockIdx.x * 256 + threadIdx.x;
  if (i < n) deg[i] = rsqrtf(deg[i]);
}

// ---------------- per-edge norm = dinv[row]*dinv[col] (reused 2 layers) ----------------
__global__ void k_wnorm(const int* __restrict__ row, const int* __restrict__ col,
                        const float* __restrict__ dinv, float* __restrict__ wn, int e) {
  int i = blockIdx.x * 256 + threadIdx.x;
  if (i < e) wn[i] = dinv[row[i]] * dinv[col[i]];
}

// ---------------- GEMM: out[n,64] = in[n,64] @ W[64,64] ----------------
// 64 rows/block, 256 threads, 4x4 register tile per thread.
// IsT padded stride 68 -> conflict-free ds_read_b128 on both operands.
#define IST 68
__global__ __launch_bounds__(256) void k_gemm(const float* __restrict__ in,
                                              const float* __restrict__ W,
                                              float* __restrict__ out, int n) {
  __shared__ float Ws[64 * 64];
  __shared__ float IsT[64 * IST];
  int tid = threadIdx.x;
  int row0 = blockIdx.x * 64;
  for (int j = tid; j < 4096; j += 256) Ws[j] = W[j];
  // stage 64 input rows, transposed: IsT[k*IST + r] = in[row0+r][k]
  for (int s = 0; s < 4; ++s) {
    int g = tid * 4 + s * 1024;  // flat float idx in 64x64 tile
    int r = g >> 6;
    int kb = g & 63;
    float4 v = make_float4(0.f, 0.f, 0.f, 0.f);
    if (row0 + r < n) v = *(const float4*)(&in[(size_t)(row0 + r) * 64 + kb]);
    IsT[(kb + 0) * IST + r] = v.x;
    IsT[(kb + 1) * IST + r] = v.y;
    IsT[(kb + 2) * IST + r] = v.z;
    IsT[(kb + 3) * IST + r] = v.w;
  }
  __syncthreads();
  int dgrp = tid & 15;  // cols d = dgrp*4 + i
  int rq = tid >> 4;    // rows r = rq*4 + j
  float4 acc0 = {0.f, 0.f, 0.f, 0.f}, acc1 = acc0, acc2 = acc0, acc3 = acc0;
  for (int k = 0; k < 64; ++k) {
    float4 wv = *(const float4*)(&Ws[k * 64 + dgrp * 4]);
    float4 iv = *(const float4*)(&IsT[k * IST + rq * 4]);
    acc0.x += iv.x * wv.x; acc0.y += iv.x * wv.y; acc0.z += iv.x * wv.z; acc0.w += iv.x * wv.w;
    acc1.x += iv.y * wv.x; acc1.y += iv.y * wv.y; acc1.z += iv.y * wv.z; acc1.w += iv.y * wv.w;
    acc2.x += iv.z * wv.x; acc2.y += iv.z * wv.y; acc2.z += iv.z * wv.z; acc2.w += iv.z * wv.w;
    acc3.x += iv.w * wv.x; acc3.y += iv.w * wv.y; acc3.z += iv.w * wv.z; acc3.w += iv.w * wv.w;
  }
  int rbase = row0 + rq * 4;
  if (rbase + 0 < n) *(float4*)(&out[(size_t)(rbase + 0) * 64 + dgrp * 4]) = acc0;
  if (rbase + 1 < n) *(float4*)(&out[(size_t)(rbase + 1) * 64 + dgrp * 4]) = acc1;
  if (rbase + 2 < n) *(float4*)(&out[(size_t)(rbase + 2) * 64 + dgrp * 4]) = acc2;
  if (rbase + 3 < n) *(float4*)(&out[(size_t)(rbase + 3) * 64 + dgrp * 4]) = acc3;
}

// ---------------- o = b + dinv^2 * h  (self-loop + bias init) ----------------
__global__ void k_selfinit(const float* __restrict__ h, const float* __restrict__ dinv,
                           const float* __restrict__ b, float* __restrict__ o, int n) {
  int idx = blockIdx.x * 256 + threadIdx.x;  // float4 index
  if (idx >= n * 16) return;
  int i = idx >> 4;
  int d4 = (idx & 15) * 4;
  float di = dinv[i];
  float s = di * di;
  float4 hv = *(const float4*)(&h[(size_t)idx * 4]);
  float4 bv = *(const float4*)(&b[d4]);
  float4 ov;
  ov.x = bv.x + s * hv.x;
  ov.y = bv.y + s * hv.y;
  ov.z = bv.z + s * hv.z;
  ov.w = bv.w + s * hv.w;
  *(float4*)(&o[(size_t)idx * 4]) = ov;
}

// ---------------- edge scatter: o[c] += wn[e] * h[r], one wave per edge ----------------
__global__ __launch_bounds__(256) void k_scatter(const int* __restrict__ row,
                                                 const int* __restrict__ col,
                                                 const float* __restrict__ wn,
                                                 const float* __restrict__ h,
                                                 float* __restrict__ o, int e) {
  int eid = blockIdx.x * 4 + (threadIdx.x >> 6);
  if (eid >= e) return;
  int lane = threadIdx.x & 63;
  int r = row[eid];
  int c = col[eid];
  float w = wn[eid];
  float v = h[(size_t)r * 64 + lane] * w;
  unsafeAtomicAdd(&o[(size_t)c * 64 + lane], v);
}

// ---------------- pooling: batch is sorted; 1 wave per 64-node chunk ----------------
__global__ void k_pool(const float* __restrict__ o, const int* __restrict__ batch,
                       float* __restrict__ sums, float* __restrict__ cntf, int n) {
  int d = threadIdx.x;  // 0..63
  int start = blockIdx.x * 64;
  if (start >= n) return;
  int end = min(start + 64, n);
  int curg = batch[start];
  float acc = 0.f, cnt = 0.f;
  for (int i = start; i < end; ++i) {
    int g = batch[i];
    if (g != curg) {
      unsafeAtomicAdd(&sums[curg * 64 + d], acc);
      if (d == 0) unsafeAtomicAdd(&cntf[curg], cnt);
      acc = 0.f;
      cnt = 0.f;
      curg = g;
    }
    acc += o[(size_t)i * 64 + d];
    cnt += 1.f;
  }
  unsafeAtomicAdd(&sums[curg * 64 + d], acc);
  if (d == 0) unsafeAtomicAdd(&cntf[curg], cnt);
}

// ---------------- final: out = sums / max(cnt,1) ----------------
__global__ void k_final(const float* __restrict__ sums, const float* __restrict__ cntf,
                        float* __restrict__ out) {
  int i = blockIdx.x * 256 + threadIdx.x;
  if (i < NG * DFEAT) out[i] = sums[i] / fmaxf(cntf[i >> 6], 1.0f);
}

extern "C" void kernel_launch(void* const* d_in, const int* in_sizes, int n_in,
                              void* d_out, int out_size, void* d_ws, size_t ws_size,
                              hipStream_t stream) {
  const float* x = (const float*)d_in[0];
  const int* ei = (const int*)d_in[1];
  const int* bat = (const int*)d_in[2];
  const float* W1 = (const float*)d_in[3];
  const float* b1 = (const float*)d_in[4];
  const float* W2 = (const float*)d_in[5];
  const float* b2 = (const float*)d_in[6];
  float* out = (float*)d_out;

  int n = in_sizes[0] / 64;  // 100000
  int e = in_sizes[1] / 2;   // 1000000
  const int* rowp = ei;      // sources
  const int* colp = ei + e;  // targets

  // workspace layout (floats)
  float* ws = (float*)d_ws;
  size_t off = 0;
  float* deg = ws + off;  off += (size_t)((n + 255) & ~255);
  float* cntf = ws + off; off += 256;
  float* sums = ws + off; off += 4096;
  float* wn = ws + off;   off += (size_t)((e + 255) & ~255);
  float* bufA = ws + off; off += (size_t)n * 64;
  float* bufB = ws + off; // + n*64  (total ~56 MB)

  int nbn = (n + 255) / 256;
  int nbe = (e + 255) / 256;
  int nbg = (n + 63) / 64;
  int nbo = (n * 16 + 255) / 256;

  k_init<<<nbn, 256, 0, stream>>>(deg, sums, cntf, n);
  k_deg<<<nbe, 256, 0, stream>>>(colp, deg, e);
  k_rsqrt<<<nbn, 256, 0, stream>>>(deg, n);
  k_wnorm<<<nbe, 256, 0, stream>>>(rowp, colp, deg, wn, e);

  // layer 1
  k_gemm<<<nbg, 256, 0, stream>>>(x, W1, bufA, n);
  k_selfinit<<<nbo, 256, 0, stream>>>(bufA, deg, b1, bufB, n);
  k_scatter<<<(e + 3) / 4, 256, 0, stream>>>(rowp, colp, wn, bufA, bufB, e);

  // layer 2
  k_gemm<<<nbg, 256, 0, stream>>>(bufB, W2, bufA, n);
  k_selfinit<<<nbo, 256, 0, stream>>>(bufA, deg, b2, bufB, n);
  k_scatter<<<(e + 3) / 4, 256, 0, stream>>>(rowp, colp, wn, bufA, bufB, e);

  // pool
  k_pool<<<(n + 63) / 64, 64, 0, stream>>>(bufB, bat, sums, cntf, n);
  k_final<<<(NG * DFEAT + 255) / 256, 256, 0, stream>>>(sums, cntf, out);
}

// Round 2
// 372.361 us; speedup vs baseline: 1.7748x; 1.7748x over previous
//
#include <hip/hip_runtime.h>

#define DFEAT 64
#define NG 64
#define SCAN_B 1024  // elements per scan block

// ---------------- zero: cnt[n], sums, cntf ----------------
__global__ void k_zero(int* __restrict__ cnt, float* __restrict__ sums,
                       float* __restrict__ cntf, int n) {
  int i = blockIdx.x * 256 + threadIdx.x;
  if (i < n) cnt[i] = 0;
  if (i < NG * DFEAT) sums[i] = 0.0f;
  if (i < NG) cntf[i] = 0.0f;
}

// ---------------- histogram of edge targets ----------------
__global__ void k_count(const int* __restrict__ col, int* __restrict__ cnt, int e) {
  int i = blockIdx.x * 256 + threadIdx.x;
  if (i < e) atomicAdd(&cnt[col[i]], 1);
}

// ---------------- scan pass 1: per-1024-block exclusive scan + block sums ----------------
__global__ __launch_bounds__(256) void k_scan1(const int* __restrict__ cnt,
                                               int* __restrict__ offs,
                                               int* __restrict__ bsum, int n) {
  __shared__ int sh[256];
  int tid = threadIdx.x;
  int base = blockIdx.x * SCAN_B + tid * 4;
  int4 v = make_int4(0, 0, 0, 0);
  if (base + 3 < n) v = *(const int4*)(&cnt[base]);
  int s4 = v.x + v.y + v.z + v.w;
  sh[tid] = s4;
  __syncthreads();
  for (int off = 1; off < 256; off <<= 1) {
    int t = (tid >= off) ? sh[tid - off] : 0;
    __syncthreads();
    sh[tid] += t;
    __syncthreads();
  }
  int excl = sh[tid] - s4;
  if (base + 3 < n) {
    int4 o;
    o.x = excl;
    o.y = excl + v.x;
    o.z = o.y + v.y;
    o.w = o.z + v.z;
    *(int4*)(&offs[base]) = o;
  }
  if (tid == 255) bsum[blockIdx.x] = sh[255];
}

// ---------------- scan pass 2: exclusive scan of block sums (single block) ----------------
__global__ __launch_bounds__(256) void k_scan2(int* __restrict__ bsum, int nb) {
  __shared__ int sh[256];
  int tid = threadIdx.x;
  int v = (tid < nb) ? bsum[tid] : 0;
  sh[tid] = v;
  __syncthreads();
  for (int off = 1; off < 256; off <<= 1) {
    int t = (tid >= off) ? sh[tid - off] : 0;
    __syncthreads();
    sh[tid] += t;
    __syncthreads();
  }
  if (tid < nb) bsum[tid] = sh[tid] - v;  // exclusive
}

// ---------------- scan pass 3: add block base; dinv = rsqrt(1+cnt) ----------------
__global__ void k_scan3(int* __restrict__ offs, const int* __restrict__ bsum,
                        const int* __restrict__ cnt, float* __restrict__ dinv, int n) {
  int i = blockIdx.x * 256 + threadIdx.x;
  if (i < n) {
    offs[i] += bsum[i >> 10];
    dinv[i] = rsqrtf(1.0f + (float)cnt[i]);
  }
}

// ---------------- fill CSR: srcs[pos] = row; offs becomes end-pointer ----------------
__global__ void k_fill(const int* __restrict__ row, const int* __restrict__ col,
                       int* __restrict__ offs, int* __restrict__ srcs, int e) {
  int i = blockIdx.x * 256 + threadIdx.x;
  if (i < e) {
    int pos = atomicAdd(&offs[col[i]], 1);
    srcs[pos] = row[i];
  }
}

// ---------------- GEMM: out[n,64] = in[n,64] @ W[64,64] ----------------
#define IST 68
__global__ __launch_bounds__(256) void k_gemm(const float* __restrict__ in,
                                              const float* __restrict__ W,
                                              float* __restrict__ out, int n) {
  __shared__ float Ws[64 * 64];
  __shared__ float IsT[64 * IST];
  int tid = threadIdx.x;
  int row0 = blockIdx.x * 64;
  for (int j = tid; j < 4096; j += 256) Ws[j] = W[j];
  for (int s = 0; s < 4; ++s) {
    int g = tid * 4 + s * 1024;
    int r = g >> 6;
    int kb = g & 63;
    float4 v = make_float4(0.f, 0.f, 0.f, 0.f);
    if (row0 + r < n) v = *(const float4*)(&in[(size_t)(row0 + r) * 64 + kb]);
    IsT[(kb + 0) * IST + r] = v.x;
    IsT[(kb + 1) * IST + r] = v.y;
    IsT[(kb + 2) * IST + r] = v.z;
    IsT[(kb + 3) * IST + r] = v.w;
  }
  __syncthreads();
  int dgrp = tid & 15;
  int rq = tid >> 4;
  float4 acc0 = {0.f, 0.f, 0.f, 0.f}, acc1 = acc0, acc2 = acc0, acc3 = acc0;
  for (int k = 0; k < 64; ++k) {
    float4 wv = *(const float4*)(&Ws[k * 64 + dgrp * 4]);
    float4 iv = *(const float4*)(&IsT[k * IST + rq * 4]);
    acc0.x += iv.x * wv.x; acc0.y += iv.x * wv.y; acc0.z += iv.x * wv.z; acc0.w += iv.x * wv.w;
    acc1.x += iv.y * wv.x; acc1.y += iv.y * wv.y; acc1.z += iv.y * wv.z; acc1.w += iv.y * wv.w;
    acc2.x += iv.z * wv.x; acc2.y += iv.z * wv.y; acc2.z += iv.z * wv.z; acc2.w += iv.z * wv.w;
    acc3.x += iv.w * wv.x; acc3.y += iv.w * wv.y; acc3.z += iv.w * wv.z; acc3.w += iv.w * wv.w;
  }
  int rbase = row0 + rq * 4;
  if (rbase + 0 < n) *(float4*)(&out[(size_t)(rbase + 0) * 64 + dgrp * 4]) = acc0;
  if (rbase + 1 < n) *(float4*)(&out[(size_t)(rbase + 1) * 64 + dgrp * 4]) = acc1;
  if (rbase + 2 < n) *(float4*)(&out[(size_t)(rbase + 2) * 64 + dgrp * 4]) = acc2;
  if (rbase + 3 < n) *(float4*)(&out[(size_t)(rbase + 3) * 64 + dgrp * 4]) = acc3;
}

// ---------------- gather: one wave per node ----------------
// o[c] = b + dinv[c]^2 * h[c] + sum_j dinv[c]*dinv[r_j]*h[r_j]
__global__ __launch_bounds__(256) void k_gather(const int* __restrict__ offs,
                                                const int* __restrict__ cnt,
                                                const int* __restrict__ srcs,
                                                const float* __restrict__ dinv,
                                                const float* __restrict__ h,
                                                const float* __restrict__ b,
                                                float* __restrict__ o, int n) {
  int node = blockIdx.x * 4 + (threadIdx.x >> 6);
  if (node >= n) return;
  int lane = threadIdx.x & 63;
  int end = offs[node];       // after fill, offs = segment end
  int degc = cnt[node];
  int s = end - degc;
  float dc = dinv[node];
  float acc = b[lane] + dc * dc * h[(size_t)node * 64 + lane];
  int j = 0;
  for (; j + 4 <= degc; j += 4) {
    int r0 = srcs[s + j + 0];
    int r1 = srcs[s + j + 1];
    int r2 = srcs[s + j + 2];
    int r3 = srcs[s + j + 3];
    float w0 = dinv[r0], w1 = dinv[r1], w2 = dinv[r2], w3 = dinv[r3];
    float v0 = h[(size_t)r0 * 64 + lane];
    float v1 = h[(size_t)r1 * 64 + lane];
    float v2 = h[(size_t)r2 * 64 + lane];
    float v3 = h[(size_t)r3 * 64 + lane];
    acc += dc * (w0 * v0 + w1 * v1 + w2 * v2 + w3 * v3);
  }
  for (; j < degc; ++j) {
    int r = srcs[s + j];
    acc += dc * dinv[r] * h[(size_t)r * 64 + lane];
  }
  o[(size_t)node * 64 + lane] = acc;
}

// ---------------- pooling: batch sorted; 1 wave per 64-node chunk ----------------
__global__ void k_pool(const float* __restrict__ o, const int* __restrict__ batch,
                       float* __restrict__ sums, float* __restrict__ cntf, int n) {
  int d = threadIdx.x;
  int start = blockIdx.x * 64;
  if (start >= n) return;
  int end = min(start + 64, n);
  int curg = batch[start];
  float acc = 0.f, cnt = 0.f;
  for (int i = start; i < end; ++i) {
    int g = batch[i];
    if (g != curg) {
      unsafeAtomicAdd(&sums[curg * 64 + d], acc);
      if (d == 0) unsafeAtomicAdd(&cntf[curg], cnt);
      acc = 0.f;
      cnt = 0.f;
      curg = g;
    }
    acc += o[(size_t)i * 64 + d];
    cnt += 1.f;
  }
  unsafeAtomicAdd(&sums[curg * 64 + d], acc);
  if (d == 0) unsafeAtomicAdd(&cntf[curg], cnt);
}

// ---------------- final ----------------
__global__ void k_final(const float* __restrict__ sums, const float* __restrict__ cntf,
                        float* __restrict__ out) {
  int i = blockIdx.x * 256 + threadIdx.x;
  if (i < NG * DFEAT) out[i] = sums[i] / fmaxf(cntf[i >> 6], 1.0f);
}

extern "C" void kernel_launch(void* const* d_in, const int* in_sizes, int n_in,
                              void* d_out, int out_size, void* d_ws, size_t ws_size,
                              hipStream_t stream) {
  const float* x = (const float*)d_in[0];
  const int* ei = (const int*)d_in[1];
  const int* bat = (const int*)d_in[2];
  const float* W1 = (const float*)d_in[3];
  const float* b1 = (const float*)d_in[4];
  const float* W2 = (const float*)d_in[5];
  const float* b2 = (const float*)d_in[6];
  float* out = (float*)d_out;

  int n = in_sizes[0] / 64;  // 100000
  int e = in_sizes[1] / 2;   // 1000000
  const int* rowp = ei;      // sources
  const int* colp = ei + e;  // targets

  // workspace layout (4B units), ~56.5 MB total
  char* ws = (char*)d_ws;
  size_t off = 0;
  auto alloc = [&](size_t elems) {
    void* p = ws + off;
    off += ((elems * 4 + 255) & ~(size_t)255);
    return p;
  };
  int* cnt = (int*)alloc(n);
  int* offs = (int*)alloc(n);
  int* bsum = (int*)alloc(256);
  float* dinv = (float*)alloc(n);
  float* sums = (float*)alloc(NG * DFEAT);
  float* cntf = (float*)alloc(NG);
  int* srcs = (int*)alloc(e);
  float* bufA = (float*)alloc((size_t)n * 64);
  float* bufB = (float*)alloc((size_t)n * 64);

  int nbn = (n + 255) / 256;
  int nbe = (e + 255) / 256;
  int nbs = (n + SCAN_B - 1) / SCAN_B;  // 98 scan blocks
  int nbg = (n + 63) / 64;              // gemm blocks
  int nbw = (n + 3) / 4;                // gather blocks (4 waves each)

  k_zero<<<nbn, 256, 0, stream>>>(cnt, sums, cntf, n);
  k_count<<<nbe, 256, 0, stream>>>(colp, cnt, e);
  k_scan1<<<nbs, 256, 0, stream>>>(cnt, offs, bsum, n);
  k_scan2<<<1, 256, 0, stream>>>(bsum, nbs);
  k_scan3<<<nbn, 256, 0, stream>>>(offs, bsum, cnt, dinv, n);
  k_fill<<<nbe, 256, 0, stream>>>(rowp, colp, offs, srcs, e);

  // layer 1
  k_gemm<<<nbg, 256, 0, stream>>>(x, W1, bufA, n);
  k_gather<<<nbw, 256, 0, stream>>>(offs, cnt, srcs, dinv, bufA, b1, bufB, n);

  // layer 2
  k_gemm<<<nbg, 256, 0, stream>>>(bufB, W2, bufA, n);
  k_gather<<<nbw, 256, 0, stream>>>(offs, cnt, srcs, dinv, bufA, b2, bufB, n);

  // pool
  k_pool<<<(n + 63) / 64, 64, 0, stream>>>(bufB, bat, sums, cntf, n);
  k_final<<<(NG * DFEAT + 255) / 256, 256, 0, stream>>>(sums, cntf, out);
}